// Round 9
// baseline (339.596 us; speedup 1.0000x reference)
//
#include <hip/hip_runtime.h>

#define N_AUTHORS 50000
#define N_PAPERS  100000
#define N_NODES   150000
#define N_EDGES   1200000
#define EMB       64

#define BSHIFT 10
#define K_B    ((N_NODES + 1023) >> 10)           // 147 row-buckets (1024 rows each)
#define CHUNK  4096                               // edges per A-block
#define NBLK_A ((N_EDGES + CHUNK - 1) / CHUNK)    // 293
#define NSC    (K_B * NBLK_A)                     // 43071 (bucket-major counts)

// bf16 helpers (plain ushort storage)
__device__ __forceinline__ float bf2f(ushort u) {
    return __uint_as_float(((unsigned)u) << 16);
}
__device__ __forceinline__ ushort f2bf(float f) {   // round-to-nearest-even
    unsigned u = __float_as_uint(f);
    return (ushort)((u + 0x7fffu + ((u >> 16) & 1u)) >> 16);
}

// ---------------- init: ego(f32,out) + ego(bf16 scratch) --------------------
__global__ void lgcn_init(const float* __restrict__ a,
                          const float* __restrict__ p,
                          float* __restrict__ ego_out,
                          ushort* __restrict__ x0) {
    size_t i = (size_t)blockIdx.x * blockDim.x + threadIdx.x;  // float4 index
    const size_t n4  = (size_t)N_NODES  * EMB / 4;
    const size_t au4 = (size_t)N_AUTHORS * EMB / 4;
    if (i >= n4) return;
    float4 v = (i < au4) ? ((const float4*)a)[i] : ((const float4*)p)[i - au4];
    ((float4*)ego_out)[i] = v;
    ushort4 b;
    b.x = f2bf(v.x); b.y = f2bf(v.y); b.z = f2bf(v.z); b.w = f2bf(v.w);
    ((ushort4*)x0)[i] = b;
}

// ---------------- row histogram + row_start scan ----------------------------
__global__ void lgcn_hist(const int* __restrict__ rows, unsigned* __restrict__ counts) {
    int e = blockIdx.x * blockDim.x + threadIdx.x;
    if (e >= N_EDGES) return;
    atomicAdd(&counts[rows[e]], 1u);
}

__global__ void lgcn_scan_blocks(const unsigned* __restrict__ counts,
                                 unsigned* __restrict__ row_start,
                                 unsigned* __restrict__ bsum) {
    __shared__ unsigned s[256];
    int t = threadIdx.x;
    int i = blockIdx.x * 256 + t;
    unsigned v = (i < N_NODES) ? counts[i] : 0u;
    s[t] = v;
    __syncthreads();
    for (int d = 1; d < 256; d <<= 1) {
        unsigned u = (t >= d) ? s[t - d] : 0u;
        __syncthreads();
        s[t] += u;
        __syncthreads();
    }
    if (i < N_NODES + 1) row_start[i] = s[t] - v;   // exclusive
    if (t == 255) bsum[blockIdx.x] = s[255];        // block total
}

__global__ void lgcn_scan_top(const unsigned* __restrict__ bsum,
                              unsigned* __restrict__ bsum_ex, int nb) {
    __shared__ unsigned s[1024];
    int t = threadIdx.x;
    unsigned v = (t < nb) ? bsum[t] : 0u;
    s[t] = v;
    __syncthreads();
    for (int d = 1; d < 1024; d <<= 1) {
        unsigned u = (t >= d) ? s[t - d] : 0u;
        __syncthreads();
        s[t] += u;
        __syncthreads();
    }
    bsum_ex[t] = s[t] - v;                          // exclusive
}

__global__ void lgcn_scan_add(unsigned* __restrict__ row_start,
                              const unsigned* __restrict__ bsum_ex) {
    int i = blockIdx.x * 256 + threadIdx.x;
    if (i >= N_NODES + 1) return;
    row_start[i] += bsum_ex[i >> 8];
}

// ---------------- 3-pass locality-aware edge sort ---------------------------
// A0: per-block bucket histogram (147 buckets = row>>10), bucket-major store
__global__ void lgcn_a0_hist(const int* __restrict__ rows,
                             unsigned* __restrict__ counts) {
    __shared__ unsigned h[K_B];
    int t = threadIdx.x;
    for (int i = t; i < K_B; i += blockDim.x) h[i] = 0;
    __syncthreads();
    int base = blockIdx.x * CHUNK;
    int end  = base + CHUNK; if (end > N_EDGES) end = N_EDGES;
    for (int e = base + t; e < end; e += blockDim.x)
        atomicAdd(&h[rows[e] >> BSHIFT], 1u);
    __syncthreads();
    for (int i = t; i < K_B; i += blockDim.x)
        counts[(size_t)i * NBLK_A + blockIdx.x] = h[i];
}

// exclusive scan over NSC bucket-major counts (single block, 1024 threads)
__global__ void lgcn_scan_big(const unsigned* __restrict__ counts,
                              unsigned* __restrict__ scanned) {
    __shared__ unsigned s[1024];
    const int PER = (NSC + 1023) / 1024;   // 43
    int t = threadIdx.x;
    int lo = t * PER;
    int hi = lo + PER; if (hi > NSC) hi = NSC;
    unsigned sum = 0;
    for (int i = lo; i < hi; ++i) sum += counts[i];
    s[t] = sum;
    __syncthreads();
    for (int d = 1; d < 1024; d <<= 1) {
        unsigned u = (t >= d) ? s[t - d] : 0u;
        __syncthreads();
        s[t] += u;
        __syncthreads();
    }
    unsigned run = s[t] - sum;             // exclusive prefix of this chunk
    for (int i = lo; i < hi; ++i) {
        unsigned v = counts[i];
        scanned[i] = run;
        run += v;
    }
}

// A1: bin edges into EXCLUSIVE per-(block,bucket) staging runs.
// Stage record packs (rowlo<<18 | col) into .x bits, val in .y.
__global__ void lgcn_a1_bin(const int* __restrict__ rows,
                            const int* __restrict__ cols,
                            const float* __restrict__ vals,
                            const unsigned* __restrict__ scanned,
                            float2* __restrict__ stage) {
    __shared__ unsigned cur[K_B];
    int t = threadIdx.x;
    for (int i = t; i < K_B; i += blockDim.x)
        cur[i] = scanned[(size_t)i * NBLK_A + blockIdx.x];
    __syncthreads();
    int base = blockIdx.x * CHUNK;
    int end  = base + CHUNK; if (end > N_EDGES) end = N_EDGES;
    for (int e = base + t; e < end; e += blockDim.x) {
        int r = rows[e];
        unsigned pos = atomicAdd(&cur[r >> BSHIFT], 1u);
        unsigned packed = ((unsigned)(r & 1023) << 18) | (unsigned)cols[e];
        stage[pos] = make_float2(__uint_as_float(packed), vals[e]);
    }
}

// B: one block per bucket -> place staged edges into row-sorted se.
// Writes land in a ~65KB L2-resident window -> full-line evictions.
__global__ void lgcn_place(const unsigned* __restrict__ row_start,
                           const unsigned* __restrict__ scanned,
                           const float2* __restrict__ stage,
                           float2* __restrict__ se) {
    __shared__ unsigned cur[1 << BSHIFT];
    int b  = blockIdx.x;
    int rb = b << BSHIFT;
    int nrows = N_NODES - rb; if (nrows > (1 << BSHIFT)) nrows = 1 << BSHIFT;
    int t = threadIdx.x;
    for (int i = t; i < nrows; i += blockDim.x) cur[i] = row_start[rb + i];
    __syncthreads();
    unsigned span0 = scanned[(size_t)b * NBLK_A];
    unsigned span1 = (b + 1 < K_B) ? scanned[(size_t)(b + 1) * NBLK_A] : N_EDGES;
    for (unsigned p = span0 + t; p < span1; p += blockDim.x) {
        float2 v = stage[p];
        unsigned u = __float_as_uint(v.x);
        unsigned rowlo = u >> 18;
        unsigned col   = u & 0x3FFFFu;
        unsigned pos = atomicAdd(&cur[rowlo], 1u);
        se[pos] = make_float2(__int_as_float((int)col), v.y);
    }
}

// ---------------- SpMM: one wave per row, 16-edge flat unroll ---------------
// Lane l: edge slot g=l>>4, dims d4=(l&15)*4.  16-lane group covers one
// edge's 128B row via ushort4 loads; 4 groups x 4 unroll = 16 edges with
// 4 independent se->gather chains in flight.  xor-16/32 reduce at the end.
__global__ void lgcn_spmm(const unsigned* __restrict__ rs,
                          const float2* __restrict__ se,
                          const ushort* __restrict__ x,
                          ushort* __restrict__ y) {
    int w    = blockIdx.x * (blockDim.x >> 6) + (threadIdx.x >> 6);
    int lane = threadIdx.x & 63;
    if (w >= N_NODES) return;
    unsigned j   = rs[w];
    unsigned end = rs[w + 1];
    const int g  = lane >> 4;
    const int d4 = (lane & 15) << 2;
    float a0 = 0.f, a1 = 0.f, a2 = 0.f, a3 = 0.f;

    while (j < end) {
#pragma unroll
        for (int k = 0; k < 4; ++k) {
            unsigned idx = j + 4 * k + g;      // uniform within 16-lane group
            float2 e;
            if (idx < end) e = se[idx];
            else { e.x = __int_as_float(0); e.y = 0.f; }
            ushort4 xv = *(const ushort4*)(x + ((size_t)__float_as_int(e.x) << 6) + d4);
            a0 += e.y * bf2f(xv.x); a1 += e.y * bf2f(xv.y);
            a2 += e.y * bf2f(xv.z); a3 += e.y * bf2f(xv.w);
        }
        j += 16;
    }

    // reduce across the 4 edge slots (lanes l, l^16, l^32, l^48)
    a0 += __shfl_xor(a0, 16, 64); a0 += __shfl_xor(a0, 32, 64);
    a1 += __shfl_xor(a1, 16, 64); a1 += __shfl_xor(a1, 32, 64);
    a2 += __shfl_xor(a2, 16, 64); a2 += __shfl_xor(a2, 32, 64);
    a3 += __shfl_xor(a3, 16, 64); a3 += __shfl_xor(a3, 32, 64);

    if (g == 0) {
        ushort4 o;
        o.x = f2bf(a0); o.y = f2bf(a1); o.z = f2bf(a2); o.w = f2bf(a3);
        *(ushort4*)(y + ((size_t)w << 6) + d4) = o;
    }
}

// ---------------- merge: out = 0.25*(ego + y1 + y2 + y3) --------------------
__global__ void lgcn_merge(const float* __restrict__ ego,
                           const ushort* __restrict__ y1,
                           const ushort* __restrict__ y2,
                           const ushort* __restrict__ y3,
                           float* __restrict__ out) {
    size_t i = (size_t)blockIdx.x * blockDim.x + threadIdx.x;  // x4 index
    const size_t n4 = (size_t)N_NODES * EMB / 4;
    if (i >= n4) return;
    float4  e  = ((const float4*)ego)[i];
    ushort4 b1 = ((const ushort4*)y1)[i];
    ushort4 b2 = ((const ushort4*)y2)[i];
    ushort4 b3 = ((const ushort4*)y3)[i];
    float4 r;
    r.x = 0.25f * (e.x + bf2f(b1.x) + bf2f(b2.x) + bf2f(b3.x));
    r.y = 0.25f * (e.y + bf2f(b1.y) + bf2f(b2.y) + bf2f(b3.y));
    r.z = 0.25f * (e.z + bf2f(b1.z) + bf2f(b2.z) + bf2f(b3.z));
    r.w = 0.25f * (e.w + bf2f(b1.w) + bf2f(b2.w) + bf2f(b3.w));
    ((float4*)out)[i] = r;
}

extern "C" void kernel_launch(void* const* d_in, const int* in_sizes, int n_in,
                              void* d_out, int out_size, void* d_ws, size_t ws_size,
                              hipStream_t stream) {
    const float* author = (const float*)d_in[0];
    const float* paper  = (const float*)d_in[1];
    const int*   rows   = (const int*)d_in[2];
    const int*   cols   = (const int*)d_in[3];
    const float* vals   = (const float*)d_in[4];

    float* ego_out = (float*)d_out;                           // 150000*64 f32
    float* acc     = (float*)d_out + (size_t)N_NODES * EMB;   // author||paper f32

    // workspace layout (~78.4 MB)
    char* w = (char*)d_ws;
    float2*   se        = (float2*)w;   w += (size_t)N_EDGES * sizeof(float2);       // 9.6 MB
    float2*   stage     = (float2*)w;   w += (size_t)N_EDGES * sizeof(float2);       // 9.6 MB
    ushort*   xbE       = (ushort*)w;   w += (size_t)N_NODES * EMB * sizeof(ushort); // 19.2 MB (ego bf16, reused as y3)
    ushort*   xb1       = (ushort*)w;   w += (size_t)N_NODES * EMB * sizeof(ushort); // 19.2 MB (y1)
    ushort*   xb2       = (ushort*)w;   w += (size_t)N_NODES * EMB * sizeof(ushort); // 19.2 MB (y2)
    unsigned* counts    = (unsigned*)w; w += (size_t)N_NODES * 4;                    // 0.6 MB
    unsigned* row_start = (unsigned*)w; w += (size_t)(N_NODES + 1) * 4;              // 0.6 MB
    unsigned* bsum      = (unsigned*)w; w += 1024 * 4;
    unsigned* bsum_ex   = (unsigned*)w; w += 1024 * 4;
    unsigned* bcounts   = (unsigned*)w; w += (size_t)NSC * 4;                        // 172 KB
    unsigned* bscanned  = (unsigned*)w; w += (size_t)NSC * 4;                        // 172 KB

    const int BLK = 256;
    const int NB_SCAN = (N_NODES + 1 + 255) / 256;    // 587
    const int g_edges = (N_EDGES + BLK - 1) / BLK;    // 4688
    const int g_vec   = (int)(((size_t)N_NODES * EMB / 4 + BLK - 1) / BLK);
    const int g_spmm  = (N_NODES + 3) / 4;            // 1 row/wave, 4 waves/block

    // init: ego (f32, out) + ego (bf16 scratch)
    lgcn_init<<<g_vec, BLK, 0, stream>>>(author, paper, ego_out, xbE);

    // CSR offsets
    hipMemsetAsync(counts, 0, (size_t)N_NODES * 4, stream);
    lgcn_hist<<<g_edges, BLK, 0, stream>>>(rows, counts);
    lgcn_scan_blocks<<<NB_SCAN, 256, 0, stream>>>(counts, row_start, bsum);
    lgcn_scan_top<<<1, 1024, 0, stream>>>(bsum, bsum_ex, NB_SCAN);
    lgcn_scan_add<<<NB_SCAN, 256, 0, stream>>>(row_start, bsum_ex);

    // locality-aware row-sort of edges into se
    lgcn_a0_hist<<<NBLK_A, BLK, 0, stream>>>(rows, bcounts);
    lgcn_scan_big<<<1, 1024, 0, stream>>>(bcounts, bscanned);
    lgcn_a1_bin<<<NBLK_A, BLK, 0, stream>>>(rows, cols, vals, bscanned, stage);
    lgcn_place<<<K_B, BLK, 0, stream>>>(row_start, bscanned, stage, se);

    // 3 propagation layers (bf16), no acc RMW
    lgcn_spmm<<<g_spmm, BLK, 0, stream>>>(row_start, se, xbE, xb1);
    lgcn_spmm<<<g_spmm, BLK, 0, stream>>>(row_start, se, xb1, xb2);
    lgcn_spmm<<<g_spmm, BLK, 0, stream>>>(row_start, se, xb2, xbE);  // y3 -> xbE

    // out = 0.25*(ego + y1 + y2 + y3)
    lgcn_merge<<<g_vec, BLK, 0, stream>>>(ego_out, xb1, xb2, xbE, acc);
}

// Round 10
// 275.175 us; speedup vs baseline: 1.2341x; 1.2341x over previous
//
#include <hip/hip_runtime.h>

#define N_AUTHORS 50000
#define N_PAPERS  100000
#define N_NODES   150000
#define N_EDGES   1200000
#define EMB       64

#define BSHIFT 10
#define K_B    ((N_NODES + 1023) >> 10)           // 147 row-buckets (1024 rows each)
#define CHUNK  4096                               // edges per A-block
#define NBLK_A ((N_EDGES + CHUNK - 1) / CHUNK)    // 293
#define NSC    (K_B * NBLK_A)                     // 43071 (bucket-major counts)
#define NBS1   ((NSC + 1023) / 1024)              // 43 L1-scan blocks

// bf16 helpers (plain ushort storage)
__device__ __forceinline__ float bf2f(ushort u) {
    return __uint_as_float(((unsigned)u) << 16);
}
__device__ __forceinline__ ushort f2bf(float f) {   // round-to-nearest-even
    unsigned u = __float_as_uint(f);
    return (ushort)((u + 0x7fffu + ((u >> 16) & 1u)) >> 16);
}

// ---------------- init: ego(f32,out) + ego(bf16 scratch) --------------------
__global__ void lgcn_init(const float* __restrict__ a,
                          const float* __restrict__ p,
                          float* __restrict__ ego_out,
                          ushort* __restrict__ x0) {
    size_t i = (size_t)blockIdx.x * blockDim.x + threadIdx.x;  // float4 index
    const size_t n4  = (size_t)N_NODES  * EMB / 4;
    const size_t au4 = (size_t)N_AUTHORS * EMB / 4;
    if (i >= n4) return;
    float4 v = (i < au4) ? ((const float4*)a)[i] : ((const float4*)p)[i - au4];
    ((float4*)ego_out)[i] = v;
    ushort4 b;
    b.x = f2bf(v.x); b.y = f2bf(v.y); b.z = f2bf(v.z); b.w = f2bf(v.w);
    ((ushort4*)x0)[i] = b;
}

// ---------------- per-row histogram (counts consumed by lgcn_place) ---------
__global__ void lgcn_hist(const int* __restrict__ rows, unsigned* __restrict__ counts) {
    int e = blockIdx.x * blockDim.x + threadIdx.x;
    if (e >= N_EDGES) return;
    atomicAdd(&counts[rows[e]], 1u);
}

// ---------------- bucket-major per-block histogram --------------------------
__global__ void lgcn_a0_hist(const int* __restrict__ rows,
                             unsigned* __restrict__ counts) {
    __shared__ unsigned h[K_B];
    int t = threadIdx.x;
    for (int i = t; i < K_B; i += blockDim.x) h[i] = 0;
    __syncthreads();
    int base = blockIdx.x * CHUNK;
    int end  = base + CHUNK; if (end > N_EDGES) end = N_EDGES;
    for (int e = base + t; e < end; e += blockDim.x)
        atomicAdd(&h[rows[e] >> BSHIFT], 1u);
    __syncthreads();
    for (int i = t; i < K_B; i += blockDim.x)
        counts[(size_t)i * NBLK_A + blockIdx.x] = h[i];
}

// ---------------- 2-level parallel exclusive scan over NSC entries ----------
// L1: per-block local exclusive scan + block totals
__global__ void lgcn_scan_l1(const unsigned* __restrict__ counts,
                             unsigned* __restrict__ scanned,
                             unsigned* __restrict__ btot) {
    __shared__ unsigned s[1024];
    int t = threadIdx.x;
    int i = blockIdx.x * 1024 + t;
    unsigned v = (i < NSC) ? counts[i] : 0u;
    s[t] = v;
    __syncthreads();
    for (int d = 1; d < 1024; d <<= 1) {
        unsigned u = (t >= d) ? s[t - d] : 0u;
        __syncthreads();
        s[t] += u;
        __syncthreads();
    }
    if (i < NSC) scanned[i] = s[t] - v;     // exclusive within block
    if (t == 1023) btot[blockIdx.x] = s[1023];
}

// L2: exclusive scan of the NBS1 block totals (one small block)
__global__ void lgcn_scan_l2(const unsigned* __restrict__ btot,
                             unsigned* __restrict__ btot_ex) {
    __shared__ unsigned s[64];
    int t = threadIdx.x;                     // 64 threads
    unsigned v = (t < NBS1) ? btot[t] : 0u;
    s[t] = v;
    __syncthreads();
    for (int d = 1; d < 64; d <<= 1) {
        unsigned u = (t >= d) ? s[t - d] : 0u;
        __syncthreads();
        s[t] += u;
        __syncthreads();
    }
    btot_ex[t] = s[t] - v;                   // exclusive
}

__device__ __forceinline__ unsigned scan_at(const unsigned* scanned,
                                            const unsigned* btot_ex, unsigned idx) {
    return scanned[idx] + btot_ex[idx >> 10];
}

// ---------------- A1: bin edges into EXCLUSIVE per-(block,bucket) runs ------
// Stage record packs (rowlo<<18 | col) in .x, val in .y.
__global__ void lgcn_a1_bin(const int* __restrict__ rows,
                            const int* __restrict__ cols,
                            const float* __restrict__ vals,
                            const unsigned* __restrict__ scanned,
                            const unsigned* __restrict__ btot_ex,
                            float2* __restrict__ stage) {
    __shared__ unsigned cur[K_B];
    int t = threadIdx.x;
    for (int i = t; i < K_B; i += blockDim.x)
        cur[i] = scan_at(scanned, btot_ex, (unsigned)i * NBLK_A + blockIdx.x);
    __syncthreads();
    int base = blockIdx.x * CHUNK;
    int end  = base + CHUNK; if (end > N_EDGES) end = N_EDGES;
    for (int e = base + t; e < end; e += blockDim.x) {
        int r = rows[e];
        unsigned pos = atomicAdd(&cur[r >> BSHIFT], 1u);
        unsigned packed = ((unsigned)(r & 1023) << 18) | (unsigned)cols[e];
        stage[pos] = make_float2(__uint_as_float(packed), vals[e]);
    }
}

// ---------------- B: per-bucket place; also computes row_start --------------
__global__ void lgcn_place(const unsigned* __restrict__ counts,     // per-row
                           const unsigned* __restrict__ scanned,
                           const unsigned* __restrict__ btot_ex,
                           const float2* __restrict__ stage,
                           float2* __restrict__ se,
                           unsigned* __restrict__ row_start) {
    __shared__ unsigned cur[1 << BSHIFT];
    __shared__ unsigned tsum[256];
    int b  = blockIdx.x;
    int rb = b << BSHIFT;
    int nrows = N_NODES - rb; if (nrows > (1 << BSHIFT)) nrows = 1 << BSHIFT;
    int t = threadIdx.x;

    // local exclusive scan of this bucket's 1024 row counts (4 per thread)
    unsigned c[4], s = 0;
#pragma unroll
    for (int k = 0; k < 4; ++k) {
        int i = t * 4 + k;
        c[k] = (i < nrows) ? counts[rb + i] : 0u;
        s += c[k];
    }
    tsum[t] = s;
    __syncthreads();
    for (int d = 1; d < 256; d <<= 1) {
        unsigned u = (t >= d) ? tsum[t - d] : 0u;
        __syncthreads();
        tsum[t] += u;
        __syncthreads();
    }
    unsigned base = scan_at(scanned, btot_ex, (unsigned)b * NBLK_A);
    unsigned run  = base + (tsum[t] - s);
#pragma unroll
    for (int k = 0; k < 4; ++k) {
        int i = t * 4 + k;
        if (i < nrows) {
            cur[i] = run;
            row_start[rb + i] = run;
            run += c[k];
        }
    }
    if (b == K_B - 1 && t == 0) row_start[N_NODES] = N_EDGES;
    __syncthreads();

    unsigned span1 = (b + 1 < K_B)
                   ? scan_at(scanned, btot_ex, (unsigned)(b + 1) * NBLK_A)
                   : N_EDGES;
    for (unsigned p = base + t; p < span1; p += blockDim.x) {
        float2 v = stage[p];
        unsigned u = __float_as_uint(v.x);
        unsigned rowlo = u >> 18;
        unsigned col   = u & 0x3FFFFu;
        unsigned pos = atomicAdd(&cur[rowlo], 1u);
        se[pos] = make_float2(__int_as_float((int)col), v.y);
    }
}

// ---------------- SpMM: one wave per row, 8-lane edge groups ----------------
// Lane l: edge slot g=l>>3, dims d8=(l&7)*8.  8 lanes x 16B (uint4) cover one
// edge's 128B bf16 row; 8 independent se->gather chains per iteration.
// Reduce across slots via xor 8/16/32.
__global__ void lgcn_spmm(const unsigned* __restrict__ rs,
                          const float2* __restrict__ se,
                          const ushort* __restrict__ x,
                          ushort* __restrict__ y) {
    int w    = blockIdx.x * (blockDim.x >> 6) + (threadIdx.x >> 6);
    int lane = threadIdx.x & 63;
    if (w >= N_NODES) return;
    unsigned j   = rs[w];
    unsigned end = rs[w + 1];
    const int g  = lane >> 3;
    const int d8 = (lane & 7) << 3;
    float a0=0.f,a1=0.f,a2=0.f,a3=0.f,a4=0.f,a5=0.f,a6=0.f,a7=0.f;

    while (j < end) {
        unsigned idx = j + g;
        float2 e;
        if (idx < end) e = se[idx];
        else { e.x = __int_as_float(0); e.y = 0.f; }
        const uint4 xv = *(const uint4*)(x + ((size_t)__float_as_int(e.x) << 6) + d8);
        a0 += e.y * __uint_as_float(xv.x << 16);
        a1 += e.y * __uint_as_float(xv.x & 0xffff0000u);
        a2 += e.y * __uint_as_float(xv.y << 16);
        a3 += e.y * __uint_as_float(xv.y & 0xffff0000u);
        a4 += e.y * __uint_as_float(xv.z << 16);
        a5 += e.y * __uint_as_float(xv.z & 0xffff0000u);
        a6 += e.y * __uint_as_float(xv.w << 16);
        a7 += e.y * __uint_as_float(xv.w & 0xffff0000u);
        j += 8;
    }

    a0 += __shfl_xor(a0, 8, 64); a0 += __shfl_xor(a0, 16, 64); a0 += __shfl_xor(a0, 32, 64);
    a1 += __shfl_xor(a1, 8, 64); a1 += __shfl_xor(a1, 16, 64); a1 += __shfl_xor(a1, 32, 64);
    a2 += __shfl_xor(a2, 8, 64); a2 += __shfl_xor(a2, 16, 64); a2 += __shfl_xor(a2, 32, 64);
    a3 += __shfl_xor(a3, 8, 64); a3 += __shfl_xor(a3, 16, 64); a3 += __shfl_xor(a3, 32, 64);
    a4 += __shfl_xor(a4, 8, 64); a4 += __shfl_xor(a4, 16, 64); a4 += __shfl_xor(a4, 32, 64);
    a5 += __shfl_xor(a5, 8, 64); a5 += __shfl_xor(a5, 16, 64); a5 += __shfl_xor(a5, 32, 64);
    a6 += __shfl_xor(a6, 8, 64); a6 += __shfl_xor(a6, 16, 64); a6 += __shfl_xor(a6, 32, 64);
    a7 += __shfl_xor(a7, 8, 64); a7 += __shfl_xor(a7, 16, 64); a7 += __shfl_xor(a7, 32, 64);

    if (g == 0) {
        uint4 o;
        o.x = (unsigned)f2bf(a0) | ((unsigned)f2bf(a1) << 16);
        o.y = (unsigned)f2bf(a2) | ((unsigned)f2bf(a3) << 16);
        o.z = (unsigned)f2bf(a4) | ((unsigned)f2bf(a5) << 16);
        o.w = (unsigned)f2bf(a6) | ((unsigned)f2bf(a7) << 16);
        *(uint4*)(y + ((size_t)w << 6) + d8) = o;
    }
}

// ---------------- merge: out = 0.25*(ego + y1 + y2 + y3) --------------------
__global__ void lgcn_merge(const float* __restrict__ ego,
                           const ushort* __restrict__ y1,
                           const ushort* __restrict__ y2,
                           const ushort* __restrict__ y3,
                           float* __restrict__ out) {
    size_t i = (size_t)blockIdx.x * blockDim.x + threadIdx.x;  // x4 index
    const size_t n4 = (size_t)N_NODES * EMB / 4;
    if (i >= n4) return;
    float4  e  = ((const float4*)ego)[i];
    ushort4 b1 = ((const ushort4*)y1)[i];
    ushort4 b2 = ((const ushort4*)y2)[i];
    ushort4 b3 = ((const ushort4*)y3)[i];
    float4 r;
    r.x = 0.25f * (e.x + bf2f(b1.x) + bf2f(b2.x) + bf2f(b3.x));
    r.y = 0.25f * (e.y + bf2f(b1.y) + bf2f(b2.y) + bf2f(b3.y));
    r.z = 0.25f * (e.z + bf2f(b1.z) + bf2f(b2.z) + bf2f(b3.z));
    r.w = 0.25f * (e.w + bf2f(b1.w) + bf2f(b2.w) + bf2f(b3.w));
    ((float4*)out)[i] = r;
}

extern "C" void kernel_launch(void* const* d_in, const int* in_sizes, int n_in,
                              void* d_out, int out_size, void* d_ws, size_t ws_size,
                              hipStream_t stream) {
    const float* author = (const float*)d_in[0];
    const float* paper  = (const float*)d_in[1];
    const int*   rows   = (const int*)d_in[2];
    const int*   cols   = (const int*)d_in[3];
    const float* vals   = (const float*)d_in[4];

    float* ego_out = (float*)d_out;                           // 150000*64 f32
    float* acc     = (float*)d_out + (size_t)N_NODES * EMB;   // author||paper f32

    // workspace layout (~78.5 MB)
    char* w = (char*)d_ws;
    float2*   se        = (float2*)w;   w += (size_t)N_EDGES * sizeof(float2);       // 9.6 MB
    float2*   stage     = (float2*)w;   w += (size_t)N_EDGES * sizeof(float2);       // 9.6 MB
    ushort*   xbE       = (ushort*)w;   w += (size_t)N_NODES * EMB * sizeof(ushort); // 19.2 MB (ego bf16, reused as y3)
    ushort*   xb1       = (ushort*)w;   w += (size_t)N_NODES * EMB * sizeof(ushort); // 19.2 MB (y1)
    ushort*   xb2       = (ushort*)w;   w += (size_t)N_NODES * EMB * sizeof(ushort); // 19.2 MB (y2)
    unsigned* counts    = (unsigned*)w; w += (size_t)N_NODES * 4;                    // 0.6 MB
    unsigned* row_start = (unsigned*)w; w += (size_t)(N_NODES + 1) * 4;              // 0.6 MB
    unsigned* bcounts   = (unsigned*)w; w += (size_t)NSC * 4;                        // 172 KB
    unsigned* bscanned  = (unsigned*)w; w += (size_t)NSC * 4;                        // 172 KB
    unsigned* btot      = (unsigned*)w; w += 64 * 4;
    unsigned* btot_ex   = (unsigned*)w; w += 64 * 4;

    const int BLK = 256;
    const int g_edges = (N_EDGES + BLK - 1) / BLK;    // 4688
    const int g_vec   = (int)(((size_t)N_NODES * EMB / 4 + BLK - 1) / BLK);
    const int g_spmm  = (N_NODES + 3) / 4;            // 1 row/wave, 4 waves/block

    // init: ego (f32, out) + ego (bf16 scratch)
    lgcn_init<<<g_vec, BLK, 0, stream>>>(author, paper, ego_out, xbE);

    // per-row counts (consumed by place)
    hipMemsetAsync(counts, 0, (size_t)N_NODES * 4, stream);
    lgcn_hist<<<g_edges, BLK, 0, stream>>>(rows, counts);

    // bucket-major (block,bucket) histogram + 2-level scan
    lgcn_a0_hist<<<NBLK_A, BLK, 0, stream>>>(rows, bcounts);
    lgcn_scan_l1<<<NBS1, 1024, 0, stream>>>(bcounts, bscanned, btot);
    lgcn_scan_l2<<<1, 64, 0, stream>>>(btot, btot_ex);

    // bin into exclusive staging runs, then place into row-sorted se
    lgcn_a1_bin<<<NBLK_A, BLK, 0, stream>>>(rows, cols, vals, bscanned, btot_ex, stage);
    lgcn_place<<<K_B, BLK, 0, stream>>>(counts, bscanned, btot_ex, stage, se, row_start);

    // 3 propagation layers (bf16), no acc RMW
    lgcn_spmm<<<g_spmm, BLK, 0, stream>>>(row_start, se, xbE, xb1);
    lgcn_spmm<<<g_spmm, BLK, 0, stream>>>(row_start, se, xb1, xb2);
    lgcn_spmm<<<g_spmm, BLK, 0, stream>>>(row_start, se, xb2, xbE);  // y3 -> xbE

    // out = 0.25*(ego + y1 + y2 + y3)
    lgcn_merge<<<g_vec, BLK, 0, stream>>>(ego_out, xb1, xb2, xbE, acc);
}

// Round 12
// 212.921 us; speedup vs baseline: 1.5949x; 1.2924x over previous
//
#include <hip/hip_runtime.h>

#define N_AUTHORS 50000
#define N_PAPERS  100000
#define N_NODES   150000
#define N_EDGES   1200000
#define EMB       64

#define BSHIFT 10
#define K_B    ((N_NODES + 1023) >> 10)           // 147 row-buckets (1024 rows each)
#define CHUNK  4096                               // edges per A-block
#define NBLK_A ((N_EDGES + CHUNK - 1) / CHUNK)    // 293
#define NSC    (K_B * NBLK_A)                     // 43071 (bucket-major counts)
#define NBS1   ((NSC + 1023) / 1024)              // 43 L1-scan blocks

// bf16 helpers (plain ushort storage)
__device__ __forceinline__ float bf2f(ushort u) {
    return __uint_as_float(((unsigned)u) << 16);
}
__device__ __forceinline__ ushort f2bf(float f) {   // round-to-nearest-even
    unsigned u = __float_as_uint(f);
    return (ushort)((u + 0x7fffu + ((u >> 16) & 1u)) >> 16);
}

// ---------------- init: ego(f32,out) + ego(bf16 scratch) --------------------
__global__ void lgcn_init(const float* __restrict__ a,
                          const float* __restrict__ p,
                          float* __restrict__ ego_out,
                          ushort* __restrict__ x0) {
    size_t i = (size_t)blockIdx.x * blockDim.x + threadIdx.x;  // float4 index
    const size_t n4  = (size_t)N_NODES  * EMB / 4;
    const size_t au4 = (size_t)N_AUTHORS * EMB / 4;
    if (i >= n4) return;
    float4 v = (i < au4) ? ((const float4*)a)[i] : ((const float4*)p)[i - au4];
    ((float4*)ego_out)[i] = v;
    ushort4 b;
    b.x = f2bf(v.x); b.y = f2bf(v.y); b.z = f2bf(v.z); b.w = f2bf(v.w);
    ((ushort4*)x0)[i] = b;
}

// ---------------- bucket-major per-block histogram --------------------------
__global__ void lgcn_a0_hist(const int* __restrict__ rows,
                             unsigned* __restrict__ counts) {
    __shared__ unsigned h[K_B];
    int t = threadIdx.x;
    for (int i = t; i < K_B; i += blockDim.x) h[i] = 0;
    __syncthreads();
    int base = blockIdx.x * CHUNK;
    int end  = base + CHUNK; if (end > N_EDGES) end = N_EDGES;
    for (int e = base + t; e < end; e += blockDim.x)
        atomicAdd(&h[rows[e] >> BSHIFT], 1u);
    __syncthreads();
    for (int i = t; i < K_B; i += blockDim.x)
        counts[(size_t)i * NBLK_A + blockIdx.x] = h[i];
}

// ---------------- 2-level parallel exclusive scan over NSC entries ----------
__global__ void lgcn_scan_l1(const unsigned* __restrict__ counts,
                             unsigned* __restrict__ scanned,
                             unsigned* __restrict__ btot) {
    __shared__ unsigned s[1024];
    int t = threadIdx.x;
    int i = blockIdx.x * 1024 + t;
    unsigned v = (i < NSC) ? counts[i] : 0u;
    s[t] = v;
    __syncthreads();
    for (int d = 1; d < 1024; d <<= 1) {
        unsigned u = (t >= d) ? s[t - d] : 0u;
        __syncthreads();
        s[t] += u;
        __syncthreads();
    }
    if (i < NSC) scanned[i] = s[t] - v;     // exclusive within block
    if (t == 1023) btot[blockIdx.x] = s[1023];
}

__global__ void lgcn_scan_l2(const unsigned* __restrict__ btot,
                             unsigned* __restrict__ btot_ex) {
    __shared__ unsigned s[64];
    int t = threadIdx.x;                     // 64 threads
    unsigned v = (t < NBS1) ? btot[t] : 0u;
    s[t] = v;
    __syncthreads();
    for (int d = 1; d < 64; d <<= 1) {
        unsigned u = (t >= d) ? s[t - d] : 0u;
        __syncthreads();
        s[t] += u;
        __syncthreads();
    }
    btot_ex[t] = s[t] - v;                   // exclusive
}

__device__ __forceinline__ unsigned scan_at(const unsigned* scanned,
                                            const unsigned* btot_ex, unsigned idx) {
    return scanned[idx] + btot_ex[idx >> 10];
}

// ---------------- A1: bin edges into EXCLUSIVE per-(block,bucket) runs ------
// Stage record packs (rowlo<<18 | col) in .x, val in .y.
__global__ void lgcn_a1_bin(const int* __restrict__ rows,
                            const int* __restrict__ cols,
                            const float* __restrict__ vals,
                            const unsigned* __restrict__ scanned,
                            const unsigned* __restrict__ btot_ex,
                            float2* __restrict__ stage) {
    __shared__ unsigned cur[K_B];
    int t = threadIdx.x;
    for (int i = t; i < K_B; i += blockDim.x)
        cur[i] = scan_at(scanned, btot_ex, (unsigned)i * NBLK_A + blockIdx.x);
    __syncthreads();
    int base = blockIdx.x * CHUNK;
    int end  = base + CHUNK; if (end > N_EDGES) end = N_EDGES;
    for (int e = base + t; e < end; e += blockDim.x) {
        int r = rows[e];
        unsigned pos = atomicAdd(&cur[r >> BSHIFT], 1u);
        unsigned packed = ((unsigned)(r & 1023) << 18) | (unsigned)cols[e];
        stage[pos] = make_float2(__uint_as_float(packed), vals[e]);
    }
}

// ---------------- B: per-bucket place; self-counts rows; emits row_start ----
__global__ void lgcn_place(const unsigned* __restrict__ scanned,
                           const unsigned* __restrict__ btot_ex,
                           const float2* __restrict__ stage,
                           float2* __restrict__ se,
                           unsigned* __restrict__ row_start) {
    __shared__ unsigned cur[1 << BSHIFT];
    __shared__ unsigned tsum[256];
    int b  = blockIdx.x;
    int rb = b << BSHIFT;
    int nrows = N_NODES - rb; if (nrows > (1 << BSHIFT)) nrows = 1 << BSHIFT;
    int t = threadIdx.x;

    unsigned base  = scan_at(scanned, btot_ex, (unsigned)b * NBLK_A);
    unsigned span1 = (b + 1 < K_B)
                   ? scan_at(scanned, btot_ex, (unsigned)(b + 1) * NBLK_A)
                   : N_EDGES;

    // pass 1: count this bucket's rows from the staged records (L2-hot span)
    for (int i = t; i < (1 << BSHIFT); i += 256) cur[i] = 0;
    __syncthreads();
    for (unsigned p = base + t; p < span1; p += 256)
        atomicAdd(&cur[__float_as_uint(stage[p].x) >> 18], 1u);
    __syncthreads();

    // block scan of the 1024 counts (4 per thread) -> cursors + row_start
    unsigned c[4], s = 0;
#pragma unroll
    for (int k = 0; k < 4; ++k) { c[k] = cur[t * 4 + k]; s += c[k]; }
    tsum[t] = s;
    __syncthreads();
    for (int d = 1; d < 256; d <<= 1) {
        unsigned u = (t >= d) ? tsum[t - d] : 0u;
        __syncthreads();
        tsum[t] += u;
        __syncthreads();
    }
    unsigned run = base + (tsum[t] - s);
    __syncthreads();            // everyone done reading cur before overwrite
#pragma unroll
    for (int k = 0; k < 4; ++k) {
        int i = t * 4 + k;
        cur[i] = run;
        if (i < nrows) row_start[rb + i] = run;
        run += c[k];
    }
    if (b == K_B - 1 && t == 0) row_start[N_NODES] = N_EDGES;
    __syncthreads();

    // pass 2: place into row-sorted se (writes land in ~65KB L2 window)
    for (unsigned p = base + t; p < span1; p += 256) {
        float2 v = stage[p];
        unsigned u = __float_as_uint(v.x);
        unsigned pos = atomicAdd(&cur[u >> 18], 1u);
        se[pos] = make_float2(__int_as_float((int)(u & 0x3FFFFu)), v.y);
    }
}

// ---------------- SpMM: one wave per row, 8-lane edge groups ----------------
// Lane l: edge slot g=l>>3, dims d8=(l&7)*8.  Fast path: 16 edges (2KB of
// gathers) issued back-to-back under a wave-uniform branch.  FINAL fuses the
// merge: out = 0.25*(ego + y1 + y2 + A*x).
template <int FINAL>
__global__ void lgcn_spmm(const unsigned* __restrict__ rs,
                          const float2* __restrict__ se,
                          const ushort* __restrict__ x,
                          ushort* __restrict__ y,
                          const float* __restrict__ ego,
                          const ushort* __restrict__ y1,
                          const ushort* __restrict__ y2,
                          float* __restrict__ out) {
    int w    = blockIdx.x * (blockDim.x >> 6) + (threadIdx.x >> 6);
    int lane = threadIdx.x & 63;
    if (w >= N_NODES) return;
    unsigned j   = rs[w];
    unsigned end = rs[w + 1];
    const int g  = lane >> 3;
    const int d8 = (lane & 7) << 3;
    float a0=0.f,a1=0.f,a2=0.f,a3=0.f,a4=0.f,a5=0.f,a6=0.f,a7=0.f;

#define BATCH(JBASE)                                                          \
    {                                                                         \
        unsigned idx = (JBASE) + g;                                           \
        float2 e;                                                             \
        if (idx < end) e = se[idx];                                           \
        else { e.x = __int_as_float(0); e.y = 0.f; }                          \
        const uint4 xv = *(const uint4*)(x + ((size_t)__float_as_int(e.x) << 6) + d8); \
        a0 += e.y * __uint_as_float(xv.x << 16);                              \
        a1 += e.y * __uint_as_float(xv.x & 0xffff0000u);                      \
        a2 += e.y * __uint_as_float(xv.y << 16);                              \
        a3 += e.y * __uint_as_float(xv.y & 0xffff0000u);                      \
        a4 += e.y * __uint_as_float(xv.z << 16);                              \
        a5 += e.y * __uint_as_float(xv.z & 0xffff0000u);                      \
        a6 += e.y * __uint_as_float(xv.w << 16);                              \
        a7 += e.y * __uint_as_float(xv.w & 0xffff0000u);                      \
    }

    if (end - j > 8) {          // wave-uniform: 16 edges, gathers back-to-back
        BATCH(j) BATCH(j + 8)
        j += 16;
    } else {
        BATCH(j)
        j += 8;
    }
    while (j < end) { BATCH(j) j += 8; }    // deg>16: 0.3% of rows
#undef BATCH

    a0 += __shfl_xor(a0, 8, 64); a0 += __shfl_xor(a0, 16, 64); a0 += __shfl_xor(a0, 32, 64);
    a1 += __shfl_xor(a1, 8, 64); a1 += __shfl_xor(a1, 16, 64); a1 += __shfl_xor(a1, 32, 64);
    a2 += __shfl_xor(a2, 8, 64); a2 += __shfl_xor(a2, 16, 64); a2 += __shfl_xor(a2, 32, 64);
    a3 += __shfl_xor(a3, 8, 64); a3 += __shfl_xor(a3, 16, 64); a3 += __shfl_xor(a3, 32, 64);
    a4 += __shfl_xor(a4, 8, 64); a4 += __shfl_xor(a4, 16, 64); a4 += __shfl_xor(a4, 32, 64);
    a5 += __shfl_xor(a5, 8, 64); a5 += __shfl_xor(a5, 16, 64); a5 += __shfl_xor(a5, 32, 64);
    a6 += __shfl_xor(a6, 8, 64); a6 += __shfl_xor(a6, 16, 64); a6 += __shfl_xor(a6, 32, 64);
    a7 += __shfl_xor(a7, 8, 64); a7 += __shfl_xor(a7, 16, 64); a7 += __shfl_xor(a7, 32, 64);

    if (g == 0) {
        size_t o = ((size_t)w << 6) + d8;
        if (FINAL) {
            float4 e0 = *(const float4*)(ego + o);
            float4 e1 = *(const float4*)(ego + o + 4);
            uint4  u1 = *(const uint4*)(y1 + o);
            uint4  u2 = *(const uint4*)(y2 + o);
            float4 r0, r1;
            r0.x = 0.25f * (e0.x + __uint_as_float(u1.x << 16)        + __uint_as_float(u2.x << 16)        + a0);
            r0.y = 0.25f * (e0.y + __uint_as_float(u1.x & 0xffff0000u)+ __uint_as_float(u2.x & 0xffff0000u)+ a1);
            r0.z = 0.25f * (e0.z + __uint_as_float(u1.y << 16)        + __uint_as_float(u2.y << 16)        + a2);
            r0.w = 0.25f * (e0.w + __uint_as_float(u1.y & 0xffff0000u)+ __uint_as_float(u2.y & 0xffff0000u)+ a3);
            r1.x = 0.25f * (e1.x + __uint_as_float(u1.z << 16)        + __uint_as_float(u2.z << 16)        + a4);
            r1.y = 0.25f * (e1.y + __uint_as_float(u1.z & 0xffff0000u)+ __uint_as_float(u2.z & 0xffff0000u)+ a5);
            r1.z = 0.25f * (e1.z + __uint_as_float(u1.w << 16)        + __uint_as_float(u2.w << 16)        + a6);
            r1.w = 0.25f * (e1.w + __uint_as_float(u1.w & 0xffff0000u)+ __uint_as_float(u2.w & 0xffff0000u)+ a7);
            *(float4*)(out + o)     = r0;
            *(float4*)(out + o + 4) = r1;
        } else {
            uint4 ov;
            ov.x = (unsigned)f2bf(a0) | ((unsigned)f2bf(a1) << 16);
            ov.y = (unsigned)f2bf(a2) | ((unsigned)f2bf(a3) << 16);
            ov.z = (unsigned)f2bf(a4) | ((unsigned)f2bf(a5) << 16);
            ov.w = (unsigned)f2bf(a6) | ((unsigned)f2bf(a7) << 16);
            *(uint4*)(y + o) = ov;
        }
    }
}

extern "C" void kernel_launch(void* const* d_in, const int* in_sizes, int n_in,
                              void* d_out, int out_size, void* d_ws, size_t ws_size,
                              hipStream_t stream) {
    const float* author = (const float*)d_in[0];
    const float* paper  = (const float*)d_in[1];
    const int*   rows   = (const int*)d_in[2];
    const int*   cols   = (const int*)d_in[3];
    const float* vals   = (const float*)d_in[4];

    float* ego_out = (float*)d_out;                           // 150000*64 f32
    float* acc     = (float*)d_out + (size_t)N_NODES * EMB;   // author||paper f32

    // workspace layout (~77.9 MB)
    char* w = (char*)d_ws;
    float2*   se        = (float2*)w;   w += (size_t)N_EDGES * sizeof(float2);       // 9.6 MB
    float2*   stage     = (float2*)w;   w += (size_t)N_EDGES * sizeof(float2);       // 9.6 MB
    ushort*   xbE       = (ushort*)w;   w += (size_t)N_NODES * EMB * sizeof(ushort); // 19.2 MB
    ushort*   xb1       = (ushort*)w;   w += (size_t)N_NODES * EMB * sizeof(ushort); // 19.2 MB (y1)
    ushort*   xb2       = (ushort*)w;   w += (size_t)N_NODES * EMB * sizeof(ushort); // 19.2 MB (y2)
    unsigned* row_start = (unsigned*)w; w += (size_t)(N_NODES + 1) * 4;              // 0.6 MB
    unsigned* bcounts   = (unsigned*)w; w += (size_t)NSC * 4;                        // 172 KB
    unsigned* bscanned  = (unsigned*)w; w += (size_t)NSC * 4;                        // 172 KB
    unsigned* btot      = (unsigned*)w; w += 64 * 4;
    unsigned* btot_ex   = (unsigned*)w; w += 64 * 4;

    const int BLK = 256;
    const int g_vec  = (int)(((size_t)N_NODES * EMB / 4 + BLK - 1) / BLK);
    const int g_spmm = (N_NODES + 3) / 4;             // 1 row/wave, 4 waves/block

    // init: ego (f32, out) + ego (bf16 scratch)
    lgcn_init<<<g_vec, BLK, 0, stream>>>(author, paper, ego_out, xbE);

    // bucket-major (block,bucket) histogram + 2-level scan
    lgcn_a0_hist<<<NBLK_A, BLK, 0, stream>>>(rows, bcounts);
    lgcn_scan_l1<<<NBS1, 1024, 0, stream>>>(bcounts, bscanned, btot);
    lgcn_scan_l2<<<1, 64, 0, stream>>>(btot, btot_ex);

    // bin into exclusive staging runs, then place (also emits row_start)
    lgcn_a1_bin<<<NBLK_A, BLK, 0, stream>>>(rows, cols, vals, bscanned, btot_ex, stage);
    lgcn_place<<<K_B, BLK, 0, stream>>>(bscanned, btot_ex, stage, se, row_start);

    // 3 propagation layers; last one fuses the merge
    lgcn_spmm<0><<<g_spmm, BLK, 0, stream>>>(row_start, se, xbE, xb1, nullptr, nullptr, nullptr, nullptr);
    lgcn_spmm<0><<<g_spmm, BLK, 0, stream>>>(row_start, se, xb1, xb2, nullptr, nullptr, nullptr, nullptr);
    lgcn_spmm<1><<<g_spmm, BLK, 0, stream>>>(row_start, se, xb2, nullptr, ego_out, xb1, xb2, acc);
}

// Round 13
// 207.678 us; speedup vs baseline: 1.6352x; 1.0252x over previous
//
#include <hip/hip_runtime.h>

#define N_AUTHORS 50000
#define N_PAPERS  100000
#define N_NODES   150000
#define N_EDGES   1200000
#define EMB       64

#define BSHIFT 10
#define K_B    ((N_NODES + 1023) >> 10)           // 147 row-buckets (1024 rows each)
#define CHUNK  4096                               // edges per A-block
#define NBLK_A ((N_EDGES + CHUNK - 1) / CHUNK)    // 293
#define NSC    (K_B * NBLK_A)                     // 43071 (bucket-major counts)
#define NBS1   ((NSC + 1023) / 1024)              // 43 L1-scan blocks

// bf16 helpers (plain ushort storage)
__device__ __forceinline__ float bf2f(ushort u) {
    return __uint_as_float(((unsigned)u) << 16);
}
__device__ __forceinline__ ushort f2bf(float f) {   // round-to-nearest-even
    unsigned u = __float_as_uint(f);
    return (ushort)((u + 0x7fffu + ((u >> 16) & 1u)) >> 16);
}

// ---------------- init: ego(f32,out) + ego(bf16 scratch) --------------------
__global__ void lgcn_init(const float* __restrict__ a,
                          const float* __restrict__ p,
                          float* __restrict__ ego_out,
                          ushort* __restrict__ x0) {
    size_t i = (size_t)blockIdx.x * blockDim.x + threadIdx.x;  // float4 index
    const size_t n4  = (size_t)N_NODES  * EMB / 4;
    const size_t au4 = (size_t)N_AUTHORS * EMB / 4;
    if (i >= n4) return;
    float4 v = (i < au4) ? ((const float4*)a)[i] : ((const float4*)p)[i - au4];
    ((float4*)ego_out)[i] = v;
    ushort4 b;
    b.x = f2bf(v.x); b.y = f2bf(v.y); b.z = f2bf(v.z); b.w = f2bf(v.w);
    ((ushort4*)x0)[i] = b;
}

// ---------------- bucket-major per-block histogram --------------------------
__global__ void lgcn_a0_hist(const int* __restrict__ rows,
                             unsigned* __restrict__ counts) {
    __shared__ unsigned h[K_B];
    int t = threadIdx.x;
    for (int i = t; i < K_B; i += blockDim.x) h[i] = 0;
    __syncthreads();
    int base = blockIdx.x * CHUNK;
    int end  = base + CHUNK; if (end > N_EDGES) end = N_EDGES;
    for (int e = base + t; e < end; e += blockDim.x)
        atomicAdd(&h[rows[e] >> BSHIFT], 1u);
    __syncthreads();
    for (int i = t; i < K_B; i += blockDim.x)
        counts[(size_t)i * NBLK_A + blockIdx.x] = h[i];
}

// ---------------- 2-level parallel exclusive scan over NSC entries ----------
__global__ void lgcn_scan_l1(const unsigned* __restrict__ counts,
                             unsigned* __restrict__ scanned,
                             unsigned* __restrict__ btot) {
    __shared__ unsigned s[1024];
    int t = threadIdx.x;
    int i = blockIdx.x * 1024 + t;
    unsigned v = (i < NSC) ? counts[i] : 0u;
    s[t] = v;
    __syncthreads();
    for (int d = 1; d < 1024; d <<= 1) {
        unsigned u = (t >= d) ? s[t - d] : 0u;
        __syncthreads();
        s[t] += u;
        __syncthreads();
    }
    if (i < NSC) scanned[i] = s[t] - v;     // exclusive within block
    if (t == 1023) btot[blockIdx.x] = s[1023];
}

__global__ void lgcn_scan_l2(const unsigned* __restrict__ btot,
                             unsigned* __restrict__ btot_ex) {
    __shared__ unsigned s[64];
    int t = threadIdx.x;                     // 64 threads
    unsigned v = (t < NBS1) ? btot[t] : 0u;
    s[t] = v;
    __syncthreads();
    for (int d = 1; d < 64; d <<= 1) {
        unsigned u = (t >= d) ? s[t - d] : 0u;
        __syncthreads();
        s[t] += u;
        __syncthreads();
    }
    btot_ex[t] = s[t] - v;                   // exclusive
}

__device__ __forceinline__ unsigned scan_at(const unsigned* scanned,
                                            const unsigned* btot_ex, unsigned idx) {
    return scanned[idx] + btot_ex[idx >> 10];
}

// ---------------- A1: bin edges into EXCLUSIVE per-(block,bucket) runs ------
// Stage record packs (rowlo<<18 | col) in .x, val in .y.
__global__ void lgcn_a1_bin(const int* __restrict__ rows,
                            const int* __restrict__ cols,
                            const float* __restrict__ vals,
                            const unsigned* __restrict__ scanned,
                            const unsigned* __restrict__ btot_ex,
                            float2* __restrict__ stage) {
    __shared__ unsigned cur[K_B];
    int t = threadIdx.x;
    for (int i = t; i < K_B; i += blockDim.x)
        cur[i] = scan_at(scanned, btot_ex, (unsigned)i * NBLK_A + blockIdx.x);
    __syncthreads();
    int base = blockIdx.x * CHUNK;
    int end  = base + CHUNK; if (end > N_EDGES) end = N_EDGES;
    for (int e = base + t; e < end; e += blockDim.x) {
        int r = rows[e];
        unsigned pos = atomicAdd(&cur[r >> BSHIFT], 1u);
        unsigned packed = ((unsigned)(r & 1023) << 18) | (unsigned)cols[e];
        stage[pos] = make_float2(__uint_as_float(packed), vals[e]);
    }
}

// ---------------- B: per-bucket place; self-counts rows; emits row_start ----
__global__ void lgcn_place(const unsigned* __restrict__ scanned,
                           const unsigned* __restrict__ btot_ex,
                           const float2* __restrict__ stage,
                           float2* __restrict__ se,
                           unsigned* __restrict__ row_start) {
    __shared__ unsigned cur[1 << BSHIFT];
    __shared__ unsigned tsum[256];
    int b  = blockIdx.x;
    int rb = b << BSHIFT;
    int nrows = N_NODES - rb; if (nrows > (1 << BSHIFT)) nrows = 1 << BSHIFT;
    int t = threadIdx.x;

    unsigned base  = scan_at(scanned, btot_ex, (unsigned)b * NBLK_A);
    unsigned span1 = (b + 1 < K_B)
                   ? scan_at(scanned, btot_ex, (unsigned)(b + 1) * NBLK_A)
                   : N_EDGES;

    // pass 1: count this bucket's rows from the staged records (L2-hot span)
    for (int i = t; i < (1 << BSHIFT); i += 256) cur[i] = 0;
    __syncthreads();
    for (unsigned p = base + t; p < span1; p += 256)
        atomicAdd(&cur[__float_as_uint(stage[p].x) >> 18], 1u);
    __syncthreads();

    // block scan of the 1024 counts (4 per thread) -> cursors + row_start
    unsigned c[4], s = 0;
#pragma unroll
    for (int k = 0; k < 4; ++k) { c[k] = cur[t * 4 + k]; s += c[k]; }
    tsum[t] = s;
    __syncthreads();
    for (int d = 1; d < 256; d <<= 1) {
        unsigned u = (t >= d) ? tsum[t - d] : 0u;
        __syncthreads();
        tsum[t] += u;
        __syncthreads();
    }
    unsigned run = base + (tsum[t] - s);
    __syncthreads();            // everyone done reading cur before overwrite
#pragma unroll
    for (int k = 0; k < 4; ++k) {
        int i = t * 4 + k;
        cur[i] = run;
        if (i < nrows) row_start[rb + i] = run;
        run += c[k];
    }
    if (b == K_B - 1 && t == 0) row_start[N_NODES] = N_EDGES;
    __syncthreads();

    // pass 2: place into row-sorted se (writes land in ~65KB L2 window)
    for (unsigned p = base + t; p < span1; p += 256) {
        float2 v = stage[p];
        unsigned u = __float_as_uint(v.x);
        unsigned pos = atomicAdd(&cur[u >> 18], 1u);
        se[pos] = make_float2(__int_as_float((int)(u & 0x3FFFFu)), v.y);
    }
}

// ---------------- SpMM: one wave per 2 rows, 8-lane edge groups -------------
// Lane l: edge slot g=l>>3, dims d8=(l&7)*8.  Both rows' 8-edge batches are
// issued back-to-back (16 independent gathers in flight).  FINAL fuses the
// merge: out = 0.25*(bf16ego + y1 + y2 + A*x).
template <int FINAL>
__global__ void lgcn_spmm(const unsigned* __restrict__ rs,
                          const float2* __restrict__ se,
                          const ushort* __restrict__ x,
                          ushort* __restrict__ y,
                          const ushort* __restrict__ egob,
                          const ushort* __restrict__ y1,
                          const ushort* __restrict__ y2,
                          float* __restrict__ out) {
    int w    = blockIdx.x * (blockDim.x >> 6) + (threadIdx.x >> 6);
    int lane = threadIdx.x & 63;
    int r0   = w << 1;
    if (r0 >= N_NODES) return;
    unsigned jA   = rs[r0];
    unsigned endA = rs[r0 + 1];
    unsigned jB   = endA;
    unsigned endB = rs[r0 + 2];
    const int g  = lane >> 3;
    const int d8 = (lane & 7) << 3;
    float a0=0.f,a1=0.f,a2=0.f,a3=0.f,a4=0.f,a5=0.f,a6=0.f,a7=0.f;
    float b0=0.f,b1=0.f,b2=0.f,b3=0.f,b4=0.f,b5=0.f,b6=0.f,b7=0.f;

#define BATCH8(JB, END, P)                                                    \
    {                                                                         \
        unsigned idx = (JB) + g;                                              \
        float2 e;                                                             \
        if (idx < (END)) e = se[idx];                                         \
        else { e.x = __int_as_float(0); e.y = 0.f; }                          \
        const uint4 xv = *(const uint4*)(x + ((size_t)__float_as_int(e.x) << 6) + d8); \
        P##0 += e.y * __uint_as_float(xv.x << 16);                            \
        P##1 += e.y * __uint_as_float(xv.x & 0xffff0000u);                    \
        P##2 += e.y * __uint_as_float(xv.y << 16);                            \
        P##3 += e.y * __uint_as_float(xv.y & 0xffff0000u);                    \
        P##4 += e.y * __uint_as_float(xv.z << 16);                            \
        P##5 += e.y * __uint_as_float(xv.z & 0xffff0000u);                    \
        P##6 += e.y * __uint_as_float(xv.w << 16);                            \
        P##7 += e.y * __uint_as_float(xv.w & 0xffff0000u);                    \
    }

    // both rows' first batches: 16 independent gathers in flight
    BATCH8(jA, endA, a)
    BATCH8(jB, endB, b)
    jA += 8; jB += 8;
    while (jA < endA) { BATCH8(jA, endA, a) jA += 8; }   // deg>8: ~46% of rows
    while (jB < endB) { BATCH8(jB, endB, b) jB += 8; }
#undef BATCH8

    a0 += __shfl_xor(a0, 8, 64); a0 += __shfl_xor(a0, 16, 64); a0 += __shfl_xor(a0, 32, 64);
    a1 += __shfl_xor(a1, 8, 64); a1 += __shfl_xor(a1, 16, 64); a1 += __shfl_xor(a1, 32, 64);
    a2 += __shfl_xor(a2, 8, 64); a2 += __shfl_xor(a2, 16, 64); a2 += __shfl_xor(a2, 32, 64);
    a3 += __shfl_xor(a3, 8, 64); a3 += __shfl_xor(a3, 16, 64); a3 += __shfl_xor(a3, 32, 64);
    a4 += __shfl_xor(a4, 8, 64); a4 += __shfl_xor(a4, 16, 64); a4 += __shfl_xor(a4, 32, 64);
    a5 += __shfl_xor(a5, 8, 64); a5 += __shfl_xor(a5, 16, 64); a5 += __shfl_xor(a5, 32, 64);
    a6 += __shfl_xor(a6, 8, 64); a6 += __shfl_xor(a6, 16, 64); a6 += __shfl_xor(a6, 32, 64);
    a7 += __shfl_xor(a7, 8, 64); a7 += __shfl_xor(a7, 16, 64); a7 += __shfl_xor(a7, 32, 64);
    b0 += __shfl_xor(b0, 8, 64); b0 += __shfl_xor(b0, 16, 64); b0 += __shfl_xor(b0, 32, 64);
    b1 += __shfl_xor(b1, 8, 64); b1 += __shfl_xor(b1, 16, 64); b1 += __shfl_xor(b1, 32, 64);
    b2 += __shfl_xor(b2, 8, 64); b2 += __shfl_xor(b2, 16, 64); b2 += __shfl_xor(b2, 32, 64);
    b3 += __shfl_xor(b3, 8, 64); b3 += __shfl_xor(b3, 16, 64); b3 += __shfl_xor(b3, 32, 64);
    b4 += __shfl_xor(b4, 8, 64); b4 += __shfl_xor(b4, 16, 64); b4 += __shfl_xor(b4, 32, 64);
    b5 += __shfl_xor(b5, 8, 64); b5 += __shfl_xor(b5, 16, 64); b5 += __shfl_xor(b5, 32, 64);
    b6 += __shfl_xor(b6, 8, 64); b6 += __shfl_xor(b6, 16, 64); b6 += __shfl_xor(b6, 32, 64);
    b7 += __shfl_xor(b7, 8, 64); b7 += __shfl_xor(b7, 16, 64); b7 += __shfl_xor(b7, 32, 64);

    if (g == 0) {
        size_t oA = ((size_t)r0 << 6) + d8;
        size_t oB = oA + EMB;
        if (FINAL) {
            uint4 ue, u1, u2;
            float4 r0v, r1v;
            // row A
            ue = *(const uint4*)(egob + oA);
            u1 = *(const uint4*)(y1 + oA);
            u2 = *(const uint4*)(y2 + oA);
            r0v.x = 0.25f * (__uint_as_float(ue.x << 16)         + __uint_as_float(u1.x << 16)         + __uint_as_float(u2.x << 16)         + a0);
            r0v.y = 0.25f * (__uint_as_float(ue.x & 0xffff0000u) + __uint_as_float(u1.x & 0xffff0000u) + __uint_as_float(u2.x & 0xffff0000u) + a1);
            r0v.z = 0.25f * (__uint_as_float(ue.y << 16)         + __uint_as_float(u1.y << 16)         + __uint_as_float(u2.y << 16)         + a2);
            r0v.w = 0.25f * (__uint_as_float(ue.y & 0xffff0000u) + __uint_as_float(u1.y & 0xffff0000u) + __uint_as_float(u2.y & 0xffff0000u) + a3);
            r1v.x = 0.25f * (__uint_as_float(ue.z << 16)         + __uint_as_float(u1.z << 16)         + __uint_as_float(u2.z << 16)         + a4);
            r1v.y = 0.25f * (__uint_as_float(ue.z & 0xffff0000u) + __uint_as_float(u1.z & 0xffff0000u) + __uint_as_float(u2.z & 0xffff0000u) + a5);
            r1v.z = 0.25f * (__uint_as_float(ue.w << 16)         + __uint_as_float(u1.w << 16)         + __uint_as_float(u2.w << 16)         + a6);
            r1v.w = 0.25f * (__uint_as_float(ue.w & 0xffff0000u) + __uint_as_float(u1.w & 0xffff0000u) + __uint_as_float(u2.w & 0xffff0000u) + a7);
            *(float4*)(out + oA)     = r0v;
            *(float4*)(out + oA + 4) = r1v;
            // row B
            ue = *(const uint4*)(egob + oB);
            u1 = *(const uint4*)(y1 + oB);
            u2 = *(const uint4*)(y2 + oB);
            r0v.x = 0.25f * (__uint_as_float(ue.x << 16)         + __uint_as_float(u1.x << 16)         + __uint_as_float(u2.x << 16)         + b0);
            r0v.y = 0.25f * (__uint_as_float(ue.x & 0xffff0000u) + __uint_as_float(u1.x & 0xffff0000u) + __uint_as_float(u2.x & 0xffff0000u) + b1);
            r0v.z = 0.25f * (__uint_as_float(ue.y << 16)         + __uint_as_float(u1.y << 16)         + __uint_as_float(u2.y << 16)         + b2);
            r0v.w = 0.25f * (__uint_as_float(ue.y & 0xffff0000u) + __uint_as_float(u1.y & 0xffff0000u) + __uint_as_float(u2.y & 0xffff0000u) + b3);
            r1v.x = 0.25f * (__uint_as_float(ue.z << 16)         + __uint_as_float(u1.z << 16)         + __uint_as_float(u2.z << 16)         + b4);
            r1v.y = 0.25f * (__uint_as_float(ue.z & 0xffff0000u) + __uint_as_float(u1.z & 0xffff0000u) + __uint_as_float(u2.z & 0xffff0000u) + b5);
            r1v.z = 0.25f * (__uint_as_float(ue.w << 16)         + __uint_as_float(u1.w << 16)         + __uint_as_float(u2.w << 16)         + b6);
            r1v.w = 0.25f * (__uint_as_float(ue.w & 0xffff0000u) + __uint_as_float(u1.w & 0xffff0000u) + __uint_as_float(u2.w & 0xffff0000u) + b7);
            *(float4*)(out + oB)     = r0v;
            *(float4*)(out + oB + 4) = r1v;
        } else {
            uint4 ov;
            ov.x = (unsigned)f2bf(a0) | ((unsigned)f2bf(a1) << 16);
            ov.y = (unsigned)f2bf(a2) | ((unsigned)f2bf(a3) << 16);
            ov.z = (unsigned)f2bf(a4) | ((unsigned)f2bf(a5) << 16);
            ov.w = (unsigned)f2bf(a6) | ((unsigned)f2bf(a7) << 16);
            *(uint4*)(y + oA) = ov;
            ov.x = (unsigned)f2bf(b0) | ((unsigned)f2bf(b1) << 16);
            ov.y = (unsigned)f2bf(b2) | ((unsigned)f2bf(b3) << 16);
            ov.z = (unsigned)f2bf(b4) | ((unsigned)f2bf(b5) << 16);
            ov.w = (unsigned)f2bf(b6) | ((unsigned)f2bf(b7) << 16);
            *(uint4*)(y + oB) = ov;
        }
    }
}

extern "C" void kernel_launch(void* const* d_in, const int* in_sizes, int n_in,
                              void* d_out, int out_size, void* d_ws, size_t ws_size,
                              hipStream_t stream) {
    const float* author = (const float*)d_in[0];
    const float* paper  = (const float*)d_in[1];
    const int*   rows   = (const int*)d_in[2];
    const int*   cols   = (const int*)d_in[3];
    const float* vals   = (const float*)d_in[4];

    float* ego_out = (float*)d_out;                           // 150000*64 f32
    float* acc     = (float*)d_out + (size_t)N_NODES * EMB;   // author||paper f32

    // workspace layout (~77.9 MB)
    char* w = (char*)d_ws;
    float2*   se        = (float2*)w;   w += (size_t)N_EDGES * sizeof(float2);       // 9.6 MB
    float2*   stage     = (float2*)w;   w += (size_t)N_EDGES * sizeof(float2);       // 9.6 MB
    ushort*   xbE       = (ushort*)w;   w += (size_t)N_NODES * EMB * sizeof(ushort); // 19.2 MB
    ushort*   xb1       = (ushort*)w;   w += (size_t)N_NODES * EMB * sizeof(ushort); // 19.2 MB (y1)
    ushort*   xb2       = (ushort*)w;   w += (size_t)N_NODES * EMB * sizeof(ushort); // 19.2 MB (y2)
    unsigned* row_start = (unsigned*)w; w += (size_t)(N_NODES + 1) * 4;              // 0.6 MB
    unsigned* bcounts   = (unsigned*)w; w += (size_t)NSC * 4;                        // 172 KB
    unsigned* bscanned  = (unsigned*)w; w += (size_t)NSC * 4;                        // 172 KB
    unsigned* btot      = (unsigned*)w; w += 64 * 4;
    unsigned* btot_ex   = (unsigned*)w; w += 64 * 4;

    const int BLK = 256;
    const int g_vec  = (int)(((size_t)N_NODES * EMB / 4 + BLK - 1) / BLK);
    const int g_spmm = ((N_NODES / 2) + 3) / 4;       // 2 rows/wave, 4 waves/block

    // init: ego (f32, out) + ego (bf16 scratch)
    lgcn_init<<<g_vec, BLK, 0, stream>>>(author, paper, ego_out, xbE);

    // bucket-major (block,bucket) histogram + 2-level scan
    lgcn_a0_hist<<<NBLK_A, BLK, 0, stream>>>(rows, bcounts);
    lgcn_scan_l1<<<NBS1, 1024, 0, stream>>>(bcounts, bscanned, btot);
    lgcn_scan_l2<<<1, 64, 0, stream>>>(btot, btot_ex);

    // bin into exclusive staging runs, then place (also emits row_start)
    lgcn_a1_bin<<<NBLK_A, BLK, 0, stream>>>(rows, cols, vals, bscanned, btot_ex, stage);
    lgcn_place<<<K_B, BLK, 0, stream>>>(bscanned, btot_ex, stage, se, row_start);

    // 3 propagation layers; last one fuses the merge (bf16 ego stream)
    lgcn_spmm<0><<<g_spmm, BLK, 0, stream>>>(row_start, se, xbE, xb1, nullptr, nullptr, nullptr, nullptr);
    lgcn_spmm<0><<<g_spmm, BLK, 0, stream>>>(row_start, se, xb1, xb2, nullptr, nullptr, nullptr, nullptr);
    lgcn_spmm<1><<<g_spmm, BLK, 0, stream>>>(row_start, se, xb2, nullptr, xbE, xb1, xb2, acc);
}